// Round 4
// baseline (1388.198 us; speedup 1.0000x reference)
//
#include <hip/hip_runtime.h>
#include <math.h>

#define NROWS 8192
#define DIN   1536
#define DH    4096
#define DOUT  2048
#define KCB   8192

typedef _Float16 h8 __attribute__((ext_vector_type(8)));
typedef _Float16 h4 __attribute__((ext_vector_type(4)));
typedef float    f4 __attribute__((ext_vector_type(4)));
typedef unsigned int u32;
typedef unsigned long long u64;

// async global->LDS 16B per lane; lds base is wave-uniform, HW adds lane*16
__device__ __forceinline__ void g2l16(const _Float16* g, char* ldsBase) {
    __builtin_amdgcn_global_load_lds(
        (const __attribute__((address_space(1))) u32*)g,
        (__attribute__((address_space(3))) u32*)ldsBase, 16, 0, 0);
}

// ---------------------------------------------------------------------------
// split fp32 -> (hi fp16, lo = true residual fp16) with exact pow2 pre-scale
// ---------------------------------------------------------------------------
__global__ __launch_bounds__(256) void split_scale_kernel(
    const float* __restrict__ src, _Float16* __restrict__ hi,
    _Float16* __restrict__ lo, float scale)
{
    size_t i = ((size_t)blockIdx.x * 256 + threadIdx.x) * 4;
    float4 v = *(const float4*)(src + i);
    float a0 = v.x * scale, a1 = v.y * scale, a2 = v.z * scale, a3 = v.w * scale;
    h4 vh, vl;
    _Float16 h0 = (_Float16)a0; vh[0] = h0; vl[0] = (_Float16)(a0 - (float)h0);
    _Float16 h1 = (_Float16)a1; vh[1] = h1; vl[1] = (_Float16)(a1 - (float)h1);
    _Float16 h2 = (_Float16)a2; vh[2] = h2; vl[2] = (_Float16)(a2 - (float)h2);
    _Float16 h3 = (_Float16)a3; vh[3] = h3; vl[3] = (_Float16)(a3 - (float)h3);
    *(h4*)(hi + i) = vh;
    *(h4*)(lo + i) = vl;
}

// hi-only conversion (codebook: rescore uses fp32 CB, lo plane unused)
__global__ __launch_bounds__(256) void tofp16_scale_kernel(
    const float* __restrict__ src, _Float16* __restrict__ hi, float scale)
{
    size_t i = ((size_t)blockIdx.x * 256 + threadIdx.x) * 4;
    float4 v = *(const float4*)(src + i);
    h4 vh;
    vh[0] = (_Float16)(v.x * scale); vh[1] = (_Float16)(v.y * scale);
    vh[2] = (_Float16)(v.z * scale); vh[3] = (_Float16)(v.w * scale);
    *(h4*)(hi + i) = vh;
}

// ---------------------------------------------------------------------------
// Split-fp16 MFMA GEMM, merged accumulator: dot = Ah*Bh + Ah*Bl + Al*Bh all
// into ONE f32 acc (lo = true residual). 128x128 tile, 4 waves, BK=32.
// LDS k-chunk slots rotated by (row>>2)&3 (inverse perm applied on the
// global source address) -> fragment ds_read_b128 is 2-way = conflict-free.
// ---------------------------------------------------------------------------
__global__ __launch_bounds__(256, 3) void gemm_split_kernel(
    const _Float16* __restrict__ Ah, const _Float16* __restrict__ Al,
    const _Float16* __restrict__ Bh, const _Float16* __restrict__ Bl,
    const float* __restrict__ bias, float biasScale,
    _Float16* __restrict__ Ch, _Float16* __restrict__ Cl,
    int M, int N, int K)
{
    __shared__ __align__(16) char lds[32768];
    const int tid = threadIdx.x;
    const int w = tid >> 6, lane = tid & 63;
    const int ln = lane & 15, q = lane >> 4;
    const int bm0 = blockIdx.y * 128, bn0 = blockIdx.x * 128;
    const int wm = (w >> 1) * 64, wn = (w & 1) * 64;

    const int sr = lane >> 2, sc = lane & 3;
    const int scp = (sc - (sr >> 2)) & 3;   // swizzled source k-chunk
    const _Float16* gsrc[4][2];
    u32 ldst[4][2];
    const _Float16* planes[4] = {Ah, Al, Bh, Bl};
#pragma unroll
    for (int p = 0; p < 4; ++p) {
        int rowBase = (p < 2) ? bm0 : bn0;
#pragma unroll
        for (int i = 0; i < 2; ++i) {
            int g = w * 2 + i;
            gsrc[p][i] = planes[p] + (size_t)(rowBase + g * 16 + sr) * K + scp * 8;
            ldst[p][i] = p * 8192 + g * 1024;
        }
    }
    const int rot = ((q + (ln >> 2)) & 3) * 16;  // reader-side slot rotation

    f4 acc[4][4] = {};
    for (int k0 = 0; k0 < K; k0 += 32) {
#pragma unroll
        for (int p = 0; p < 4; ++p)
#pragma unroll
            for (int i = 0; i < 2; ++i)
                g2l16(gsrc[p][i] + k0, lds + ldst[p][i]);
        __syncthreads();
        h8 ah[4], al[4], bh[4], bl[4];
#pragma unroll
        for (int t = 0; t < 4; ++t) {
            int ar = wm + t * 16 + ln;
            int br = wn + t * 16 + ln;
            ah[t] = *(const h8*)(lds + 0     + ar * 64 + rot);
            al[t] = *(const h8*)(lds + 8192  + ar * 64 + rot);
            bh[t] = *(const h8*)(lds + 16384 + br * 64 + rot);
            bl[t] = *(const h8*)(lds + 24576 + br * 64 + rot);
        }
#pragma unroll
        for (int i = 0; i < 4; ++i)
#pragma unroll
            for (int j = 0; j < 4; ++j) {
                acc[i][j] = __builtin_amdgcn_mfma_f32_16x16x32_f16(al[i], bh[j], acc[i][j], 0, 0, 0);
                acc[i][j] = __builtin_amdgcn_mfma_f32_16x16x32_f16(ah[i], bl[j], acc[i][j], 0, 0, 0);
                acc[i][j] = __builtin_amdgcn_mfma_f32_16x16x32_f16(ah[i], bh[j], acc[i][j], 0, 0, 0);
            }
        __syncthreads();
    }

    // epilogue: C/D layout col = lane&15, row = q*4 + reg
#pragma unroll
    for (int tn = 0; tn < 4; ++tn) {
        int col = bn0 + wn + tn * 16 + ln;
        float bb = bias[col] * biasScale;
#pragma unroll
        for (int tm = 0; tm < 4; ++tm) {
#pragma unroll
            for (int r = 0; r < 4; ++r) {
                int row = bm0 + wm + tm * 16 + q * 4 + r;
                float v = acc[tm][tn][r] + bb;
                _Float16 hi = (_Float16)v;
                _Float16 lo = (_Float16)(v - (float)hi);
                Ch[(size_t)row * N + col] = hi;
                Cl[(size_t)row * N + col] = lo;
            }
        }
    }
}

// ---------------------------------------------------------------------------
// Pass A: hh-only approx score GEMM -> u8 quantized score matrix.
// delta = -acc*2^-12; approx err (dropped lo terms) <= ~2e-5 << u8 capture
// window 1.2e-3. Same LDS swizzle as gemm_split.
// ---------------------------------------------------------------------------
__global__ __launch_bounds__(256, 4) void gemm_hh_u8_kernel(
    const _Float16* __restrict__ Ah, const _Float16* __restrict__ Bh,
    unsigned char* __restrict__ S, int M, int N, int K)
{
    __shared__ __align__(16) char lds[16384];
    const int tid = threadIdx.x;
    const int w = tid >> 6, lane = tid & 63;
    const int ln = lane & 15, q = lane >> 4;
    const int bm0 = blockIdx.y * 128, bn0 = blockIdx.x * 128;
    const int wm = (w >> 1) * 64, wn = (w & 1) * 64;

    const int sr = lane >> 2, sc = lane & 3;
    const int scp = (sc - (sr >> 2)) & 3;
    const _Float16* ga[2];
    const _Float16* gb[2];
    u32 la[2], lb[2];
#pragma unroll
    for (int i = 0; i < 2; ++i) {
        int g = w * 2 + i;
        ga[i] = Ah + (size_t)(bm0 + g * 16 + sr) * K + scp * 8;
        gb[i] = Bh + (size_t)(bn0 + g * 16 + sr) * K + scp * 8;
        la[i] = g * 1024;
        lb[i] = 8192 + g * 1024;
    }
    const int rot = ((q + (ln >> 2)) & 3) * 16;

    f4 acc[4][4] = {};
    for (int k0 = 0; k0 < K; k0 += 32) {
#pragma unroll
        for (int i = 0; i < 2; ++i) {
            g2l16(ga[i] + k0, lds + la[i]);
            g2l16(gb[i] + k0, lds + lb[i]);
        }
        __syncthreads();
        h8 a[4], b[4];
#pragma unroll
        for (int t = 0; t < 4; ++t) {
            a[t] = *(const h8*)(lds + (wm + t * 16 + ln) * 64 + rot);
            b[t] = *(const h8*)(lds + 8192 + (wn + t * 16 + ln) * 64 + rot);
        }
#pragma unroll
        for (int i = 0; i < 4; ++i)
#pragma unroll
            for (int j = 0; j < 4; ++j)
                acc[i][j] = __builtin_amdgcn_mfma_f32_16x16x32_f16(a[i], b[j], acc[i][j], 0, 0, 0);
        __syncthreads();
    }

#pragma unroll
    for (int tn = 0; tn < 4; ++tn) {
        int col = bn0 + wn + tn * 16 + ln;
#pragma unroll
        for (int tm = 0; tm < 4; ++tm) {
            int row0 = bm0 + wm + tm * 16 + q * 4;
#pragma unroll
            for (int r = 0; r < 4; ++r) {
                float delta = acc[tm][tn][r] * -0.000244140625f;
                float qf = (delta + 0.0768f) * (1.0f / 0.0006f);
                int qi = (int)(qf + 0.5f);
                qi = qi < 0 ? 0 : (qi > 255 ? 255 : qi);
                S[(size_t)(row0 + r) * N + col] = (unsigned char)qi;
            }
        }
    }
}

// ---------------------------------------------------------------------------
// Pass B: per row: u8 min -> candidates (q <= min+3, cap 128) -> exact fp32
// rescore score = fl(1536 - 2*dot) -> packed min (ties: lowest index) ->
// copy codebook row to out.
// ---------------------------------------------------------------------------
__global__ __launch_bounds__(256) void select_rescore_kernel(
    const unsigned char* __restrict__ S,
    const _Float16* __restrict__ zh, const _Float16* __restrict__ zl,
    const float* __restrict__ CB, float* __restrict__ out)
{
    const int row = blockIdx.x;
    const int t = threadIdx.x;
    __shared__ float zsh[DOUT];
    __shared__ int cand[128];
    __shared__ int ncand;
    __shared__ u32 mred[4];
    __shared__ float wred[4];
    __shared__ u64 bestsh;

    {
        h8 vh = *(const h8*)(zh + (size_t)row * DOUT + t * 8);
        h8 vl = *(const h8*)(zl + (size_t)row * DOUT + t * 8);
#pragma unroll
        for (int j = 0; j < 8; ++j)
            zsh[t * 8 + j] = (float)vh[j] + (float)vl[j];
    }
    if (t == 0) ncand = 0;

    const uchar4* sr4 = (const uchar4*)(S + (size_t)row * KCB);
    u32 mn = 255;
    uchar4 loc[8];
#pragma unroll
    for (int i = 0; i < 8; ++i) {
        uchar4 v = sr4[t + i * 256];
        loc[i] = v;
        u32 m0 = v.x < v.y ? v.x : v.y;
        u32 m1 = v.z < v.w ? v.z : v.w;
        m0 = m0 < m1 ? m0 : m1;
        mn = m0 < mn ? m0 : mn;
    }
#pragma unroll
    for (int o = 32; o > 0; o >>= 1) { u32 x = __shfl_down(mn, o, 64); mn = x < mn ? x : mn; }
    if ((t & 63) == 0) mred[t >> 6] = mn;
    __syncthreads();
    u32 qmin = mred[0];
    qmin = mred[1] < qmin ? mred[1] : qmin;
    qmin = mred[2] < qmin ? mred[2] : qmin;
    qmin = mred[3] < qmin ? mred[3] : qmin;
    const u32 thr = qmin + 3;

#pragma unroll
    for (int i = 0; i < 8; ++i) {
        uchar4 v = loc[i];
        int base = (t + i * 256) * 4;
        if (v.x <= thr) { int p = atomicAdd(&ncand, 1); if (p < 128) cand[p] = base; }
        if (v.y <= thr) { int p = atomicAdd(&ncand, 1); if (p < 128) cand[p] = base + 1; }
        if (v.z <= thr) { int p = atomicAdd(&ncand, 1); if (p < 128) cand[p] = base + 2; }
        if (v.w <= thr) { int p = atomicAdd(&ncand, 1); if (p < 128) cand[p] = base + 3; }
    }
    __syncthreads();
    int nc = ncand; nc = nc > 128 ? 128 : nc;

    u64 best = 0xFFFFFFFFFFFFFFFFull;
    for (int c = 0; c < nc; ++c) {
        const int k = cand[c];
        const float* cb = CB + (size_t)k * DOUT;
        float part = 0.f;
        float4 p0 = *(const float4*)(cb + t * 8);
        float4 p1 = *(const float4*)(cb + t * 8 + 4);
        part += zsh[t * 8 + 0] * p0.x; part += zsh[t * 8 + 1] * p0.y;
        part += zsh[t * 8 + 2] * p0.z; part += zsh[t * 8 + 3] * p0.w;
        part += zsh[t * 8 + 4] * p1.x; part += zsh[t * 8 + 5] * p1.y;
        part += zsh[t * 8 + 6] * p1.z; part += zsh[t * 8 + 7] * p1.w;
#pragma unroll
        for (int o = 32; o > 0; o >>= 1) part += __shfl_down(part, o, 64);
        if ((t & 63) == 0) wred[t >> 6] = part;
        __syncthreads();
        if (t == 0) {
            float dot = (wred[0] + wred[1]) + (wred[2] + wred[3]);
            float s = fmaf(dot, -2.0f, 1536.0f);
            u32 u = __float_as_uint(s);
            u = (u & 0x80000000u) ? ~u : (u | 0x80000000u);
            u64 key = ((u64)u << 32) | (u32)k;
            best = key < best ? key : best;
        }
        __syncthreads();
    }
    if (t == 0) bestsh = best;
    __syncthreads();
    const int bidx = (int)(bestsh & 0xFFFFFFFFu);
    const float4* src = (const float4*)(CB + (size_t)bidx * DOUT);
    float4* dst = (float4*)(out + (size_t)row * DOUT);
    dst[t] = src[t];
    dst[t + 256] = src[t + 256];
}

// ---------------------------------------------------------------------------
// LayerNorm (+GELU) on split input (scaled by 64), writes split (scale 1).
// ---------------------------------------------------------------------------
template <int GELU, int DMAX>
__global__ __launch_bounds__(256) void ln_split_kernel(
    _Float16* __restrict__ Xh, _Float16* __restrict__ Xl,
    const float* __restrict__ gg, const float* __restrict__ bb, int D)
{
    constexpr int CH = DMAX / 2048;
    const int row = blockIdx.x;
    _Float16* xh = Xh + (size_t)row * D;
    _Float16* xl = Xl + (size_t)row * D;
    const int t = threadIdx.x;
    __shared__ float sred[4];

    float vals[CH * 8];
    float s = 0.f;
#pragma unroll
    for (int c = 0; c < CH; ++c) {
        h8 vh = *(const h8*)(xh + c * 2048 + t * 8);
        h8 vl = *(const h8*)(xl + c * 2048 + t * 8);
#pragma unroll
        for (int j = 0; j < 8; ++j) {
            float v = ((float)vh[j] + (float)vl[j]) * 0.015625f;
            vals[c * 8 + j] = v;
            s += v;
        }
    }
#pragma unroll
    for (int o = 32; o > 0; o >>= 1) s += __shfl_down(s, o, 64);
    if ((t & 63) == 0) sred[t >> 6] = s;
    __syncthreads();
    const float mu = (sred[0] + sred[1] + sred[2] + sred[3]) / (float)D;
    __syncthreads();

    float s2 = 0.f;
#pragma unroll
    for (int i = 0; i < CH * 8; ++i) { float d = vals[i] - mu; s2 += d * d; }
#pragma unroll
    for (int o = 32; o > 0; o >>= 1) s2 += __shfl_down(s2, o, 64);
    if ((t & 63) == 0) sred[t >> 6] = s2;
    __syncthreads();
    const float var = (sred[0] + sred[1] + sred[2] + sred[3]) / (float)D;
    const float inv = 1.0f / sqrtf(var + 1e-5f);

#pragma unroll
    for (int c = 0; c < CH; ++c) {
        int base = c * 2048 + t * 8;
        float4 g0 = *(const float4*)(gg + base);
        float4 g1 = *(const float4*)(gg + base + 4);
        float4 b0 = *(const float4*)(bb + base);
        float4 b1 = *(const float4*)(bb + base + 4);
        float gv[8] = {g0.x, g0.y, g0.z, g0.w, g1.x, g1.y, g1.z, g1.w};
        float bv[8] = {b0.x, b0.y, b0.z, b0.w, b1.x, b1.y, b1.z, b1.w};
        h8 oh, ol;
#pragma unroll
        for (int j = 0; j < 8; ++j) {
            float y = (vals[c * 8 + j] - mu) * inv * gv[j] + bv[j];
            if (GELU) y = 0.5f * y * (1.0f + erff(y * 0.70710678118654752f));
            _Float16 hi = (_Float16)y;
            oh[j] = hi;
            ol[j] = (_Float16)(y - (float)hi);
        }
        *(h8*)(xh + base) = oh;
        *(h8*)(xl + base) = ol;
    }
}

extern "C" void kernel_launch(void* const* d_in, const int* in_sizes, int n_in,
                              void* d_out, int out_size, void* d_ws, size_t ws_size,
                              hipStream_t stream)
{
    const float* latents = (const float*)d_in[0];
    const float* W1      = (const float*)d_in[1];
    const float* b1      = (const float*)d_in[2];
    const float* g1      = (const float*)d_in[3];
    const float* be1     = (const float*)d_in[4];
    const float* W2      = (const float*)d_in[5];
    const float* b2      = (const float*)d_in[6];
    const float* g2      = (const float*)d_in[7];
    const float* be2     = (const float*)d_in[8];
    const float* CB      = (const float*)d_in[9];
    float* out = (float*)d_out;

    char* ws = (char*)d_ws;
    // region A [0, 75.5M): lat+W1 splits; later z split
    _Float16* lath = (_Float16*)(ws + 0);
    _Float16* latl = (_Float16*)(ws + 25165824);
    _Float16* W1h  = (_Float16*)(ws + 50331648);
    _Float16* W1l  = (_Float16*)(ws + 62914560);
    _Float16* zh   = (_Float16*)(ws + 0);
    _Float16* zl   = (_Float16*)(ws + 33554432);
    // region D [75.5M, 209.7M): h split; later CBh + S8 (h dead after GEMM2)
    _Float16* hh   = (_Float16*)(ws + 75497472);
    _Float16* hl   = (_Float16*)(ws + 142606336);
    _Float16* CBh  = (_Float16*)(ws + 75497472);     // 33.5 MB
    unsigned char* S8 = (unsigned char*)(ws + 109051904);  // 67.1 MB, ends 176.2M
    // region B [209.7M, 243.3M): W2 split
    _Float16* W2h  = (_Float16*)(ws + 209715200);
    _Float16* W2l  = (_Float16*)(ws + 226492416);

    dim3 blk(256);
    split_scale_kernel<<<(NROWS * DIN) / 1024, blk, 0, stream>>>(latents, lath, latl, 1.0f);
    split_scale_kernel<<<(DH * DIN) / 1024, blk, 0, stream>>>(W1, W1h, W1l, 64.0f);
    split_scale_kernel<<<(DOUT * DH) / 1024, blk, 0, stream>>>(W2, W2h, W2l, 64.0f);

    gemm_split_kernel<<<dim3(DH / 128, NROWS / 128), blk, 0, stream>>>(
        lath, latl, W1h, W1l, b1, 64.0f, hh, hl, NROWS, DH, DIN);
    ln_split_kernel<1, DH><<<NROWS, blk, 0, stream>>>(hh, hl, g1, be1, DH);

    gemm_split_kernel<<<dim3(DOUT / 128, NROWS / 128), blk, 0, stream>>>(
        hh, hl, W2h, W2l, b2, 64.0f, zh, zl, NROWS, DOUT, DH);

    // CB hi-plane into dead h region (after GEMM2 consumed h)
    tofp16_scale_kernel<<<(KCB * DOUT) / 1024, blk, 0, stream>>>(CB, CBh, 8192.0f);

    ln_split_kernel<0, DOUT><<<NROWS, blk, 0, stream>>>(zh, zl, g2, be2, DOUT);

    // pass A: hh-only approx scores -> u8 matrix
    gemm_hh_u8_kernel<<<dim3(KCB / 128, NROWS / 128), blk, 0, stream>>>(
        zh, CBh, S8, NROWS, KCB, DOUT);

    // pass B: candidate select + exact rescore + gather
    select_rescore_kernel<<<NROWS, blk, 0, stream>>>(S8, zh, zl, CB, out);
}